// Round 6
// baseline (519.050 us; speedup 1.0000x reference)
//
#include <hip/hip_runtime.h>

typedef short s8v __attribute__((ext_vector_type(8)));
typedef float f4v __attribute__((ext_vector_type(4)));

#define N_PIX 16384
#define NE    8192
#define EDIM  256
#define ZQ_ELEMS 4194304
#define MARGIN 4.5e-4f

__device__ __forceinline__ float bf2f(unsigned short u) {
    union { unsigned int i; float f; } c; c.i = ((unsigned int)u) << 16; return c.f;
}
__device__ __forceinline__ unsigned short f2bf(float f) {
    unsigned int u = __float_as_uint(f);
    u = (u + 0x7fffu + ((u >> 16) & 1u)) >> 16;   // RNE
    return (unsigned short)u;
}
__device__ __forceinline__ unsigned short f2bf_down(float f) {  // round toward -inf
    unsigned int u = __float_as_uint(f);
    unsigned short b = (unsigned short)(u >> 16);
    if ((u & 0xFFFFu) && (u >> 31)) b += 1;
    return b;
}

// numpy pairwise_sum over 128 squared elements (exact replication: 8
// accumulators, fixed combine tree), f32 RN ops, no FMA contraction.
__device__ __forceinline__ float np_pw128sq(const float* a) {
    float r[8];
    #pragma unroll
    for (int j = 0; j < 8; ++j) r[j] = __fmul_rn(a[j], a[j]);
    for (int i = 8; i < 128; i += 8)
        #pragma unroll
        for (int j = 0; j < 8; ++j) r[j] = __fadd_rn(r[j], __fmul_rn(a[i + j], a[i + j]));
    return __fadd_rn(__fadd_rn(__fadd_rn(r[0], r[1]), __fadd_rn(r[2], r[3])),
                     __fadd_rn(__fadd_rn(r[4], r[5]), __fadd_rn(r[6], r[7])));
}

// K0: cb16 = bf16(cb); esum32[k] = np.sum(cb[k]*cb[k]) in exact np-f32
// pairwise semantics. WS-only writes.
__global__ __launch_bounds__(256) void vq_prep(const float* __restrict__ cb,
                                               unsigned short* __restrict__ cb16,
                                               float* __restrict__ esum32) {
    int t = threadIdx.x;
    int base = blockIdx.x * 64;
    const float* src = cb + (size_t)base * EDIM;
    unsigned short* dst = cb16 + (size_t)base * EDIM;
    for (int i = 0; i < 64; ++i) dst[i * EDIM + t] = f2bf(src[i * EDIM + t]);
    if (t < 64) {
        const float* a = cb + (size_t)(base + t) * EDIM;
        esum32[base + t] = __fadd_rn(np_pw128sq(a), np_pw128sq(a + 128));
    }
}

// K1: MFMA pruning. Block = 8 waves owns 64 pixels; wave w owns codes
// [w*1024,(w+1)*1024) in 32-code groups. gmin[group][pixel] =
// bf16_down(-2*max dot). Worst-case proxy error (bf16 quant of z,e +
// dropped esum + bf16 storage) <= ~1.1e-4 each side; MARGIN covers
// 2*err + f32 ulp(256)=3.05e-5 with 2x slack. WS-only writes.
__global__ __launch_bounds__(512, 2) void vq_phase1(const float* __restrict__ z,
                                                    const unsigned short* __restrict__ cb16,
                                                    unsigned short* __restrict__ gmin) {
    const int t = threadIdx.x;
    const int wave = t >> 6, lane = t & 63;
    const int col = lane & 15, q = lane >> 4;
    const int mb = blockIdx.x * 64;

    // A frags: A[m=lane&15][k=q*8+j]; pixel n = mb + rt*16 + m (z NCHW f32).
    s8v A[4][8];
    #pragma unroll
    for (int rt = 0; rt < 4; ++rt) {
        int n = mb + rt * 16 + col;
        const float* zb = z + ((size_t)(n >> 10) << 18) + (size_t)(n & 1023);
        #pragma unroll
        for (int c0 = 0; c0 < 8; ++c0) {
            s8v a;
            #pragma unroll
            for (int j = 0; j < 8; ++j) {
                int c = c0 * 32 + q * 8 + j;
                a[j] = (short)f2bf(zb[(size_t)c << 10]);
            }
            A[rt][c0] = a;
        }
    }

    for (int it = 0; it < 32; ++it) {
        int n0 = wave * 1024 + it * 32;
        const unsigned short* bb = cb16 + (size_t)(n0 + col) * EDIM + q * 8;
        f4v zz = {0.f, 0.f, 0.f, 0.f};
        f4v acc[4][2];
        #pragma unroll
        for (int rt = 0; rt < 4; ++rt) { acc[rt][0] = zz; acc[rt][1] = zz; }
        #pragma unroll
        for (int c0 = 0; c0 < 8; ++c0) {
            s8v B0 = *(const s8v*)(bb + c0 * 32);
            s8v B1 = *(const s8v*)(bb + 16 * EDIM + c0 * 32);
            #pragma unroll
            for (int rt = 0; rt < 4; ++rt) {
                acc[rt][0] = __builtin_amdgcn_mfma_f32_16x16x32_bf16(A[rt][c0], B0, acc[rt][0], 0, 0, 0);
                acc[rt][1] = __builtin_amdgcn_mfma_f32_16x16x32_bf16(A[rt][c0], B1, acc[rt][1], 0, 0, 0);
            }
        }
        // D: col=lane&15 (code), row=q*4+r (pixel within 16-tile)
        #pragma unroll
        for (int rt = 0; rt < 4; ++rt) {
            #pragma unroll
            for (int r = 0; r < 4; ++r) {
                float mx = fmaxf(acc[rt][0][r], acc[rt][1][r]);
                #pragma unroll
                for (int m = 1; m < 16; m <<= 1) mx = fmaxf(mx, __shfl_xor(mx, m));
                if (col == rt * 4 + r)
                    gmin[(size_t)(wave * 32 + it) * N_PIX + mb + rt * 16 + q * 4 + r] =
                        f2bf_down(-2.0f * mx);
            }
        }
    }
}

// K2: rescore candidate groups replicating np f32 semantics:
// d = f32(f32(zsum + esum[k]) - f32(2 * f32(dot64))), argmin with
// FIRST-INDEX tie-break (== np.argmin over quantized d). One wave/16 px.
__global__ __launch_bounds__(64) void vq_phase2(const float* __restrict__ z,
                                                const float* __restrict__ cb,
                                                const float* __restrict__ esum32,
                                                const unsigned short* __restrict__ gmin,
                                                unsigned int* __restrict__ idxw) {
    __shared__ float zt[16 * 260];
    __shared__ unsigned short gm[256 * 17];
    __shared__ float zs[16];
    int lane = threadIdx.x;
    int p0 = blockIdx.x * 16;
    int bb = p0 >> 10, inner = p0 & 1023;

    for (int i = 0; i < 64; ++i) {
        int c = i * 4 + (lane >> 4), p = lane & 15;
        zt[p * 260 + c] = z[((size_t)(bb * 256 + c) << 10) + inner + p];
    }
    for (int i = 0; i < 64; ++i) {
        int g = i * 4 + (lane >> 4), p = lane & 15;
        gm[g * 17 + p] = gmin[(size_t)g * N_PIX + p0 + p];
    }
    __syncthreads();
    if (lane < 16) {
        const float* a = zt + lane * 260;
        zs[lane] = __fadd_rn(np_pw128sq(a), np_pw128sq(a + 128));  // np zsum
    }
    __syncthreads();

    for (int p = 0; p < 16; ++p) {
        float lmin = 3.0e38f;
        #pragma unroll
        for (int j = 0; j < 4; ++j) lmin = fminf(lmin, bf2f(gm[(lane * 4 + j) * 17 + p]));
        #pragma unroll
        for (int m = 1; m < 64; m <<= 1) lmin = fminf(lmin, __shfl_xor(lmin, m));
        float thr = lmin + MARGIN;
        float zsp = zs[p];

        float bd = 3.0e38f; int bk = 0x7FFFFFFF;
        for (int j = 0; j < 4; ++j) {
            unsigned long long mask = __ballot(bf2f(gm[(lane * 4 + j) * 17 + p]) <= thr);
            while (mask) {
                int lb = __builtin_ctzll(mask); mask &= mask - 1;
                int g = lb * 4 + j;
                int k = g * 32 + (lane & 31);
                int h = lane >> 5;
                const float* cr = cb + (size_t)k * EDIM + h * 128;
                const float* zr = zt + p * 260 + h * 128;
                double s = 0.0;
                #pragma unroll 8
                for (int i = 0; i < 128; ++i) s = fma((double)zr[i], (double)cr[i], s);
                s += __shfl_xor(s, 32);
                float E = (float)s;                                   // einsum f32 surrogate
                float d = __fsub_rn(__fadd_rn(zsp, esum32[k]), __fmul_rn(2.0f, E));
                int ki = k;
                #pragma unroll
                for (int m = 1; m < 64; m <<= 1) {
                    float od = __shfl_xor(d, m); int ok = __shfl_xor(ki, m);
                    if (od < d || (od == d && ok < ki)) { d = od; ki = ok; }
                }
                if (d < bd || (d == bd && ki < bk)) { bd = d; bk = ki; }
            }
        }
        if (lane == 0) idxw[p0 + p] = (unsigned int)bk;
    }
}

// K3: SOLE writer of z_q (f32 chunk0) and indices (f32 chunk2).
__global__ __launch_bounds__(256) void vq_emit(const float* __restrict__ cb,
                                               const float* __restrict__ z,
                                               const unsigned int* __restrict__ idxw,
                                               float* __restrict__ outf,
                                               float* __restrict__ lossw) {
    __shared__ float red[4];
    int t = threadIdx.x;
    int gtid = blockIdx.x * 256 + t;
    if (gtid < N_PIX) outf[ZQ_ELEMS + 1 + gtid] = (float)(idxw[gtid] & (NE - 1));

    float acc = 0.f;
    size_t base = (size_t)blockIdx.x * 16384;
    for (int i = 0; i < 64; ++i) {
        size_t o = base + (size_t)i * 256 + t;
        int b = (int)(o >> 18);
        int c = (int)((o >> 10) & 255);
        int p = (int)(o & 1023);
        int idx = (int)(idxw[b * 1024 + p] & (NE - 1));
        float qv = cb[(size_t)idx * EDIM + c];
        outf[o] = qv;
        float d = qv - z[o];
        acc = fmaf(d, d, acc);
    }
    #pragma unroll
    for (int off = 32; off > 0; off >>= 1) acc += __shfl_down(acc, off);
    if ((t & 63) == 0) red[t >> 6] = acc;
    __syncthreads();
    if (t == 0) atomicAdd(lossw, red[0] + red[1] + red[2] + red[3]);
}

// K4: SOLE writer of loss (f32 chunk1).
__global__ void vq_finalize(const float* __restrict__ lossw, float* __restrict__ loss_out) {
    loss_out[0] = 1.25f * lossw[0] * (1.0f / 4194304.0f);
}

extern "C" void kernel_launch(void* const* d_in, const int* in_sizes, int n_in,
                              void* d_out, int out_size, void* d_ws, size_t ws_size,
                              hipStream_t stream) {
    const float* z  = (const float*)d_in[0];   // f32 [16,256,32,32]
    const float* cb = (const float*)d_in[1];   // f32 [8192,256]
    float* outf = (float*)d_out;               // f32 [z_q | loss | indices]

    char* w = (char*)d_ws;
    unsigned short* cb16   = (unsigned short*)w;               //  4,194,304 B
    float*          esum32 = (float*)(w + 4194304);            //     32,768 B
    unsigned short* gmin   = (unsigned short*)(w + 4227072);   //  8,388,608 B
    unsigned int*   idxw   = (unsigned int*)(w + 12615680);    //     65,536 B
    float*          lossw  = (float*)(w + 12681216);           //          4 B

    if (ws_size < 12681220) return;  // diagnostic: all-zero out => ws too small

    hipMemsetAsync(lossw, 0, sizeof(float), stream);
    vq_prep    <<<NE / 64, 256, 0, stream>>>(cb, cb16, esum32);
    vq_phase1  <<<N_PIX / 64, 512, 0, stream>>>(z, cb16, gmin);
    vq_phase2  <<<N_PIX / 16, 64, 0, stream>>>(z, cb, esum32, gmin, idxw);
    vq_emit    <<<256, 256, 0, stream>>>(cb, z, idxw, outf, lossw);
    vq_finalize<<<1, 1, 0, stream>>>(lossw, outf + ZQ_ELEMS);
}

// Round 7
// 477.181 us; speedup vs baseline: 1.0877x; 1.0877x over previous
//
#include <hip/hip_runtime.h>

typedef short s8v __attribute__((ext_vector_type(8)));
typedef float f4v __attribute__((ext_vector_type(4)));

#define N_PIX 16384
#define NE    8192
#define EDIM  256
#define ZQ_ELEMS 4194304
#define MARGIN 4.5e-4f

__device__ __forceinline__ float bf2f(unsigned short u) {
    union { unsigned int i; float f; } c; c.i = ((unsigned int)u) << 16; return c.f;
}
__device__ __forceinline__ unsigned short f2bf(float f) {
    unsigned int u = __float_as_uint(f);
    u = (u + 0x7fffu + ((u >> 16) & 1u)) >> 16;   // RNE
    return (unsigned short)u;
}
__device__ __forceinline__ unsigned short f2bf_down(float f) {  // round toward -inf
    unsigned int u = __float_as_uint(f);
    unsigned short b = (unsigned short)(u >> 16);
    if ((u & 0xFFFFu) && (u >> 31)) b += 1;
    return b;
}

// numpy pairwise_sum over 128 squared elements (exact replication: 8
// accumulators, fixed combine tree), f32 RN ops, no FMA contraction.
__device__ __forceinline__ float np_pw128sq(const float* a) {
    float r[8];
    #pragma unroll
    for (int j = 0; j < 8; ++j) r[j] = __fmul_rn(a[j], a[j]);
    for (int i = 8; i < 128; i += 8)
        #pragma unroll
        for (int j = 0; j < 8; ++j) r[j] = __fadd_rn(r[j], __fmul_rn(a[i + j], a[i + j]));
    return __fadd_rn(__fadd_rn(__fadd_rn(r[0], r[1]), __fadd_rn(r[2], r[3])),
                     __fadd_rn(__fadd_rn(r[4], r[5]), __fadd_rn(r[6], r[7])));
}

// K0: cb16 = bf16(cb); esum32[k] = np.sum(cb[k]*cb[k]) in exact np-f32
// pairwise semantics. WS-only writes.
__global__ __launch_bounds__(256) void vq_prep(const float* __restrict__ cb,
                                               unsigned short* __restrict__ cb16,
                                               float* __restrict__ esum32) {
    int t = threadIdx.x;
    int base = blockIdx.x * 64;
    const float* src = cb + (size_t)base * EDIM;
    unsigned short* dst = cb16 + (size_t)base * EDIM;
    for (int i = 0; i < 64; ++i) dst[i * EDIM + t] = f2bf(src[i * EDIM + t]);
    if (t < 64) {
        const float* a = cb + (size_t)(base + t) * EDIM;
        esum32[base + t] = __fadd_rn(np_pw128sq(a), np_pw128sq(a + 128));
    }
}

// K1: MFMA pruning. Block = 8 waves owns 64 pixels; wave w owns codes
// [w*1024,(w+1)*1024) in 32-code groups. gmin[group][pixel] =
// bf16_down(-2*max dot). Worst-case proxy error (bf16 quant of z,e +
// dropped esum + bf16 storage) <= ~1.1e-4 each side; MARGIN covers
// 2*err + f32 ulp(256)=3.05e-5 with 2x slack. WS-only writes.
__global__ __launch_bounds__(512, 2) void vq_phase1(const float* __restrict__ z,
                                                    const unsigned short* __restrict__ cb16,
                                                    unsigned short* __restrict__ gmin) {
    const int t = threadIdx.x;
    const int wave = t >> 6, lane = t & 63;
    const int col = lane & 15, q = lane >> 4;
    const int mb = blockIdx.x * 64;

    // A frags: A[m=lane&15][k=q*8+j]; pixel n = mb + rt*16 + m (z NCHW f32).
    s8v A[4][8];
    #pragma unroll
    for (int rt = 0; rt < 4; ++rt) {
        int n = mb + rt * 16 + col;
        const float* zb = z + ((size_t)(n >> 10) << 18) + (size_t)(n & 1023);
        #pragma unroll
        for (int c0 = 0; c0 < 8; ++c0) {
            s8v a;
            #pragma unroll
            for (int j = 0; j < 8; ++j) {
                int c = c0 * 32 + q * 8 + j;
                a[j] = (short)f2bf(zb[(size_t)c << 10]);
            }
            A[rt][c0] = a;
        }
    }

    for (int it = 0; it < 32; ++it) {
        int n0 = wave * 1024 + it * 32;
        const unsigned short* bb = cb16 + (size_t)(n0 + col) * EDIM + q * 8;
        f4v zz = {0.f, 0.f, 0.f, 0.f};
        f4v acc[4][2];
        #pragma unroll
        for (int rt = 0; rt < 4; ++rt) { acc[rt][0] = zz; acc[rt][1] = zz; }
        #pragma unroll
        for (int c0 = 0; c0 < 8; ++c0) {
            s8v B0 = *(const s8v*)(bb + c0 * 32);
            s8v B1 = *(const s8v*)(bb + 16 * EDIM + c0 * 32);
            #pragma unroll
            for (int rt = 0; rt < 4; ++rt) {
                acc[rt][0] = __builtin_amdgcn_mfma_f32_16x16x32_bf16(A[rt][c0], B0, acc[rt][0], 0, 0, 0);
                acc[rt][1] = __builtin_amdgcn_mfma_f32_16x16x32_bf16(A[rt][c0], B1, acc[rt][1], 0, 0, 0);
            }
        }
        // D: col=lane&15 (code), row=q*4+r (pixel within 16-tile)
        #pragma unroll
        for (int rt = 0; rt < 4; ++rt) {
            #pragma unroll
            for (int r = 0; r < 4; ++r) {
                float mx = fmaxf(acc[rt][0][r], acc[rt][1][r]);
                #pragma unroll
                for (int m = 1; m < 16; m <<= 1) mx = fmaxf(mx, __shfl_xor(mx, m));
                if (col == rt * 4 + r)
                    gmin[(size_t)(wave * 32 + it) * N_PIX + mb + rt * 16 + q * 4 + r] =
                        f2bf_down(-2.0f * mx);
            }
        }
    }
}

// K2: rescore candidate groups replicating np f32 semantics:
// d = f32(f32(zsum + esum[k]) - f32(2 * f32(dot64))), argmin with
// FIRST-INDEX tie-break (== np.argmin over quantized d).
// 4 waves/block; block owns 16 pixels, wave w owns pixels 4w..4w+3.
__global__ __launch_bounds__(256) void vq_phase2(const float* __restrict__ z,
                                                 const float* __restrict__ cb,
                                                 const float* __restrict__ esum32,
                                                 const unsigned short* __restrict__ gmin,
                                                 unsigned int* __restrict__ idxw) {
    __shared__ float zt[16 * 260];
    __shared__ unsigned short gm[256 * 17];
    __shared__ float zs[16];
    int t = threadIdx.x;
    int wave = t >> 6, lane = t & 63;
    int p0 = blockIdx.x * 16;
    int bb = p0 >> 10, inner = p0 & 1023;

    #pragma unroll
    for (int i = 0; i < 16; ++i) {
        int c = i * 16 + (t >> 4), p = t & 15;
        zt[p * 260 + c] = z[((size_t)(bb * 256 + c) << 10) + inner + p];
    }
    #pragma unroll
    for (int i = 0; i < 16; ++i) {
        int g = i * 16 + (t >> 4), p = t & 15;
        gm[g * 17 + p] = gmin[(size_t)g * N_PIX + p0 + p];
    }
    __syncthreads();
    if (t < 16) {
        const float* a = zt + t * 260;
        zs[t] = __fadd_rn(np_pw128sq(a), np_pw128sq(a + 128));  // np zsum
    }
    __syncthreads();

    #pragma unroll
    for (int pp = 0; pp < 4; ++pp) {
        int p = wave * 4 + pp;
        float lmin = 3.0e38f;
        #pragma unroll
        for (int j = 0; j < 4; ++j) lmin = fminf(lmin, bf2f(gm[(lane * 4 + j) * 17 + p]));
        #pragma unroll
        for (int m = 1; m < 64; m <<= 1) lmin = fminf(lmin, __shfl_xor(lmin, m));
        float thr = lmin + MARGIN;
        float zsp = zs[p];

        float bd = 3.0e38f; int bk = 0x7FFFFFFF;
        for (int j = 0; j < 4; ++j) {
            unsigned long long mask = __ballot(bf2f(gm[(lane * 4 + j) * 17 + p]) <= thr);
            while (mask) {
                int lb = __builtin_ctzll(mask); mask &= mask - 1;
                int g = lb * 4 + j;
                int k = g * 32 + (lane & 31);
                int h = lane >> 5;
                const float* cr = cb + (size_t)k * EDIM + h * 128;
                const float* zr = zt + p * 260 + h * 128;
                double s = 0.0;
                #pragma unroll 8
                for (int i = 0; i < 128; ++i) s = fma((double)zr[i], (double)cr[i], s);
                s += __shfl_xor(s, 32);
                float E = (float)s;                                   // einsum f32 surrogate
                float d = __fsub_rn(__fadd_rn(zsp, esum32[k]), __fmul_rn(2.0f, E));
                int ki = k;
                #pragma unroll
                for (int m = 1; m < 64; m <<= 1) {
                    float od = __shfl_xor(d, m); int ok = __shfl_xor(ki, m);
                    if (od < d || (od == d && ok < ki)) { d = od; ki = ok; }
                }
                if (d < bd || (d == bd && ki < bk)) { bd = d; bk = ki; }
            }
        }
        if (lane == 0) idxw[p0 + p] = (unsigned int)bk;
    }
}

// K3: SOLE writer of z_q (f32 chunk0) and indices (f32 chunk2).
__global__ __launch_bounds__(256) void vq_emit(const float* __restrict__ cb,
                                               const float* __restrict__ z,
                                               const unsigned int* __restrict__ idxw,
                                               float* __restrict__ outf,
                                               float* __restrict__ lossw) {
    __shared__ float red[4];
    int t = threadIdx.x;
    int gtid = blockIdx.x * 256 + t;
    if (gtid < N_PIX) outf[ZQ_ELEMS + 1 + gtid] = (float)(idxw[gtid] & (NE - 1));

    float acc = 0.f;
    size_t base = (size_t)blockIdx.x * 16384;
    for (int i = 0; i < 64; ++i) {
        size_t o = base + (size_t)i * 256 + t;
        int b = (int)(o >> 18);
        int c = (int)((o >> 10) & 255);
        int p = (int)(o & 1023);
        int idx = (int)(idxw[b * 1024 + p] & (NE - 1));
        float qv = cb[(size_t)idx * EDIM + c];
        outf[o] = qv;
        float d = qv - z[o];
        acc = fmaf(d, d, acc);
    }
    #pragma unroll
    for (int off = 32; off > 0; off >>= 1) acc += __shfl_down(acc, off);
    if ((t & 63) == 0) red[t >> 6] = acc;
    __syncthreads();
    if (t == 0) atomicAdd(lossw, red[0] + red[1] + red[2] + red[3]);
}

// K4: SOLE writer of loss (f32 chunk1).
__global__ void vq_finalize(const float* __restrict__ lossw, float* __restrict__ loss_out) {
    loss_out[0] = 1.25f * lossw[0] * (1.0f / 4194304.0f);
}

extern "C" void kernel_launch(void* const* d_in, const int* in_sizes, int n_in,
                              void* d_out, int out_size, void* d_ws, size_t ws_size,
                              hipStream_t stream) {
    const float* z  = (const float*)d_in[0];   // f32 [16,256,32,32]
    const float* cb = (const float*)d_in[1];   // f32 [8192,256]
    float* outf = (float*)d_out;               // f32 [z_q | loss | indices]

    char* w = (char*)d_ws;
    unsigned short* cb16   = (unsigned short*)w;               //  4,194,304 B
    float*          esum32 = (float*)(w + 4194304);            //     32,768 B
    unsigned short* gmin   = (unsigned short*)(w + 4227072);   //  8,388,608 B
    unsigned int*   idxw   = (unsigned int*)(w + 12615680);    //     65,536 B
    float*          lossw  = (float*)(w + 12681216);           //          4 B

    if (ws_size < 12681220) return;  // diagnostic: all-zero out => ws too small

    hipMemsetAsync(lossw, 0, sizeof(float), stream);
    vq_prep    <<<NE / 64, 256, 0, stream>>>(cb, cb16, esum32);
    vq_phase1  <<<N_PIX / 64, 512, 0, stream>>>(z, cb16, gmin);
    vq_phase2  <<<N_PIX / 16, 256, 0, stream>>>(z, cb, esum32, gmin, idxw);
    vq_emit    <<<256, 256, 0, stream>>>(cb, z, idxw, outf, lossw);
    vq_finalize<<<1, 1, 0, stream>>>(lossw, outf + ZQ_ELEMS);
}

// Round 8
// 439.763 us; speedup vs baseline: 1.1803x; 1.0851x over previous
//
#include <hip/hip_runtime.h>

typedef short s8v __attribute__((ext_vector_type(8)));
typedef float f4v __attribute__((ext_vector_type(4)));
typedef float f4 __attribute__((ext_vector_type(4)));

#define N_PIX 16384
#define NE    8192
#define EDIM  256
#define ZQ_ELEMS 4194304
#define MARGIN 4.5e-4f

__device__ __forceinline__ float bf2f(unsigned short u) {
    union { unsigned int i; float f; } c; c.i = ((unsigned int)u) << 16; return c.f;
}
__device__ __forceinline__ unsigned short f2bf(float f) {
    unsigned int u = __float_as_uint(f);
    u = (u + 0x7fffu + ((u >> 16) & 1u)) >> 16;   // RNE
    return (unsigned short)u;
}
__device__ __forceinline__ unsigned short f2bf_down(float f) {  // round toward -inf
    unsigned int u = __float_as_uint(f);
    unsigned short b = (unsigned short)(u >> 16);
    if ((u & 0xFFFFu) && (u >> 31)) b += 1;
    return b;
}

// numpy pairwise_sum over 128 squared elements (exact replication: 8
// accumulators, fixed combine tree), f32 RN ops, no FMA contraction.
__device__ __forceinline__ float np_pw128sq(const float* a) {
    float r[8];
    #pragma unroll
    for (int j = 0; j < 8; ++j) r[j] = __fmul_rn(a[j], a[j]);
    for (int i = 8; i < 128; i += 8)
        #pragma unroll
        for (int j = 0; j < 8; ++j) r[j] = __fadd_rn(r[j], __fmul_rn(a[i + j], a[i + j]));
    return __fadd_rn(__fadd_rn(__fadd_rn(r[0], r[1]), __fadd_rn(r[2], r[3])),
                     __fadd_rn(__fadd_rn(r[4], r[5]), __fadd_rn(r[6], r[7])));
}

// K0: cb16 = bf16(cb); esum32[k] = np.sum(cb[k]*cb[k]) in exact np-f32
// pairwise semantics. WS-only writes.
__global__ __launch_bounds__(256) void vq_prep(const float* __restrict__ cb,
                                               unsigned short* __restrict__ cb16,
                                               float* __restrict__ esum32) {
    int t = threadIdx.x;
    int base = blockIdx.x * 64;
    const float* src = cb + (size_t)base * EDIM;
    unsigned short* dst = cb16 + (size_t)base * EDIM;
    for (int i = 0; i < 64; ++i) dst[i * EDIM + t] = f2bf(src[i * EDIM + t]);
    if (t < 64) {
        const float* a = cb + (size_t)(base + t) * EDIM;
        esum32[base + t] = __fadd_rn(np_pw128sq(a), np_pw128sq(a + 128));
    }
}

// K1: MFMA pruning. Block = 8 waves owns 64 pixels; wave w owns codes
// [w*1024,(w+1)*1024) in 32-code groups. gmin[group][pixel] =
// bf16_down(-2*max dot). Worst-case proxy error (bf16 quant of z,e +
// dropped esum + bf16 storage) <= ~1.1e-4 each side; MARGIN covers
// 2*err + f32 ulp(256)=3.05e-5 with 2x slack. WS-only writes.
__global__ __launch_bounds__(512, 2) void vq_phase1(const float* __restrict__ z,
                                                    const unsigned short* __restrict__ cb16,
                                                    unsigned short* __restrict__ gmin) {
    const int t = threadIdx.x;
    const int wave = t >> 6, lane = t & 63;
    const int col = lane & 15, q = lane >> 4;
    const int mb = blockIdx.x * 64;

    // A frags: A[m=lane&15][k=q*8+j]; pixel n = mb + rt*16 + m (z NCHW f32).
    s8v A[4][8];
    #pragma unroll
    for (int rt = 0; rt < 4; ++rt) {
        int n = mb + rt * 16 + col;
        const float* zb = z + ((size_t)(n >> 10) << 18) + (size_t)(n & 1023);
        #pragma unroll
        for (int c0 = 0; c0 < 8; ++c0) {
            s8v a;
            #pragma unroll
            for (int j = 0; j < 8; ++j) {
                int c = c0 * 32 + q * 8 + j;
                a[j] = (short)f2bf(zb[(size_t)c << 10]);
            }
            A[rt][c0] = a;
        }
    }

    for (int it = 0; it < 32; ++it) {
        int n0 = wave * 1024 + it * 32;
        const unsigned short* bb = cb16 + (size_t)(n0 + col) * EDIM + q * 8;
        f4v zz = {0.f, 0.f, 0.f, 0.f};
        f4v acc[4][2];
        #pragma unroll
        for (int rt = 0; rt < 4; ++rt) { acc[rt][0] = zz; acc[rt][1] = zz; }
        #pragma unroll
        for (int c0 = 0; c0 < 8; ++c0) {
            s8v B0 = *(const s8v*)(bb + c0 * 32);
            s8v B1 = *(const s8v*)(bb + 16 * EDIM + c0 * 32);
            #pragma unroll
            for (int rt = 0; rt < 4; ++rt) {
                acc[rt][0] = __builtin_amdgcn_mfma_f32_16x16x32_bf16(A[rt][c0], B0, acc[rt][0], 0, 0, 0);
                acc[rt][1] = __builtin_amdgcn_mfma_f32_16x16x32_bf16(A[rt][c0], B1, acc[rt][1], 0, 0, 0);
            }
        }
        // D: col=lane&15 (code), row=q*4+r (pixel within 16-tile)
        #pragma unroll
        for (int rt = 0; rt < 4; ++rt) {
            #pragma unroll
            for (int r = 0; r < 4; ++r) {
                float mx = fmaxf(acc[rt][0][r], acc[rt][1][r]);
                #pragma unroll
                for (int m = 1; m < 16; m <<= 1) mx = fmaxf(mx, __shfl_xor(mx, m));
                if (col == rt * 4 + r)
                    gmin[(size_t)(wave * 32 + it) * N_PIX + mb + rt * 16 + q * 4 + r] =
                        f2bf_down(-2.0f * mx);
            }
        }
    }
}

// K2: rescore candidate groups replicating np f32 semantics:
// d = f32(f32(zsum + esum[k]) - f32(2 * f32(dot64))), argmin with
// FIRST-INDEX tie-break. 4 waves/block, wave owns pixels 4w..4w+3.
// Inner loop: float4 loads, 4 independent f64 accs (reassoc err ~1e-19,
// irrelevant at f32 boundaries), per-lane best + ONE deferred wave reduce.
__global__ __launch_bounds__(256) void vq_phase2(const float* __restrict__ z,
                                                 const float* __restrict__ cb,
                                                 const float* __restrict__ esum32,
                                                 const unsigned short* __restrict__ gmin,
                                                 unsigned int* __restrict__ idxw) {
    __shared__ float zt[16 * 260];
    __shared__ unsigned short gm[256 * 17];
    __shared__ float zs[16];
    int t = threadIdx.x;
    int wave = t >> 6, lane = t & 63;
    int p0 = blockIdx.x * 16;
    int bb = p0 >> 10, inner = p0 & 1023;

    #pragma unroll
    for (int i = 0; i < 16; ++i) {
        int c = i * 16 + (t >> 4), p = t & 15;
        zt[p * 260 + c] = z[((size_t)(bb * 256 + c) << 10) + inner + p];
    }
    #pragma unroll
    for (int i = 0; i < 16; ++i) {
        int g = i * 16 + (t >> 4), p = t & 15;
        gm[g * 17 + p] = gmin[(size_t)g * N_PIX + p0 + p];
    }
    __syncthreads();
    if (t < 16) {
        const float* a = zt + t * 260;
        zs[t] = __fadd_rn(np_pw128sq(a), np_pw128sq(a + 128));  // np zsum
    }
    __syncthreads();

    #pragma unroll
    for (int pp = 0; pp < 4; ++pp) {
        int p = wave * 4 + pp;
        float lmin = 3.0e38f;
        #pragma unroll
        for (int j = 0; j < 4; ++j) lmin = fminf(lmin, bf2f(gm[(lane * 4 + j) * 17 + p]));
        #pragma unroll
        for (int m = 1; m < 64; m <<= 1) lmin = fminf(lmin, __shfl_xor(lmin, m));
        float thr = lmin + MARGIN;
        float zsp = zs[p];

        float bd = 3.0e38f; int bk = 0x7FFFFFFF;
        for (int j = 0; j < 4; ++j) {
            unsigned long long mask = __ballot(bf2f(gm[(lane * 4 + j) * 17 + p]) <= thr);
            while (mask) {
                int lb = __builtin_ctzll(mask); mask &= mask - 1;
                int g = lb * 4 + j;
                int k = g * 32 + (lane & 31);
                const f4* cr = (const f4*)(cb + (size_t)k * EDIM + (lane >> 5) * 128);
                const f4* zr = (const f4*)(zt + p * 260 + (lane >> 5) * 128);
                double a0 = 0.0, a1 = 0.0, a2 = 0.0, a3 = 0.0;
                #pragma unroll 8
                for (int i = 0; i < 32; ++i) {
                    f4 x = zr[i], y = cr[i];
                    a0 = fma((double)x[0], (double)y[0], a0);
                    a1 = fma((double)x[1], (double)y[1], a1);
                    a2 = fma((double)x[2], (double)y[2], a2);
                    a3 = fma((double)x[3], (double)y[3], a3);
                }
                double s = (a0 + a1) + (a2 + a3);
                s += __shfl_xor(s, 32);
                float E = (float)s;                                   // einsum f32 surrogate
                float d = __fsub_rn(__fadd_rn(zsp, esum32[k]), __fmul_rn(2.0f, E));
                if (d < bd || (d == bd && k < bk)) { bd = d; bk = k; }
            }
        }
        #pragma unroll
        for (int m = 1; m < 64; m <<= 1) {
            float od = __shfl_xor(bd, m); int ok = __shfl_xor(bk, m);
            if (od < bd || (od == bd && ok < bk)) { bd = od; bk = ok; }
        }
        if (lane == 0) idxw[p0 + p] = (unsigned int)bk;
    }
}

// K3: SOLE writer of z_q (f32 chunk0) and indices (f32 chunk2).
__global__ __launch_bounds__(256) void vq_emit(const float* __restrict__ cb,
                                               const float* __restrict__ z,
                                               const unsigned int* __restrict__ idxw,
                                               float* __restrict__ outf,
                                               float* __restrict__ lossw) {
    __shared__ float red[4];
    int t = threadIdx.x;
    int gtid = blockIdx.x * 256 + t;
    if (gtid < N_PIX) outf[ZQ_ELEMS + 1 + gtid] = (float)(idxw[gtid] & (NE - 1));

    float acc = 0.f;
    size_t base = (size_t)blockIdx.x * 16384;
    for (int i = 0; i < 64; ++i) {
        size_t o = base + (size_t)i * 256 + t;
        int b = (int)(o >> 18);
        int c = (int)((o >> 10) & 255);
        int p = (int)(o & 1023);
        int idx = (int)(idxw[b * 1024 + p] & (NE - 1));
        float qv = cb[(size_t)idx * EDIM + c];
        outf[o] = qv;
        float d = qv - z[o];
        acc = fmaf(d, d, acc);
    }
    #pragma unroll
    for (int off = 32; off > 0; off >>= 1) acc += __shfl_down(acc, off);
    if ((t & 63) == 0) red[t >> 6] = acc;
    __syncthreads();
    if (t == 0) atomicAdd(lossw, red[0] + red[1] + red[2] + red[3]);
}

// K4: SOLE writer of loss (f32 chunk1).
__global__ void vq_finalize(const float* __restrict__ lossw, float* __restrict__ loss_out) {
    loss_out[0] = 1.25f * lossw[0] * (1.0f / 4194304.0f);
}

extern "C" void kernel_launch(void* const* d_in, const int* in_sizes, int n_in,
                              void* d_out, int out_size, void* d_ws, size_t ws_size,
                              hipStream_t stream) {
    const float* z  = (const float*)d_in[0];   // f32 [16,256,32,32]
    const float* cb = (const float*)d_in[1];   // f32 [8192,256]
    float* outf = (float*)d_out;               // f32 [z_q | loss | indices]

    char* w = (char*)d_ws;
    unsigned short* cb16   = (unsigned short*)w;               //  4,194,304 B
    float*          esum32 = (float*)(w + 4194304);            //     32,768 B
    unsigned short* gmin   = (unsigned short*)(w + 4227072);   //  8,388,608 B
    unsigned int*   idxw   = (unsigned int*)(w + 12615680);    //     65,536 B
    float*          lossw  = (float*)(w + 12681216);           //          4 B

    if (ws_size < 12681220) return;  // diagnostic: all-zero out => ws too small

    hipMemsetAsync(lossw, 0, sizeof(float), stream);
    vq_prep    <<<NE / 64, 256, 0, stream>>>(cb, cb16, esum32);
    vq_phase1  <<<N_PIX / 64, 512, 0, stream>>>(z, cb16, gmin);
    vq_phase2  <<<N_PIX / 16, 256, 0, stream>>>(z, cb, esum32, gmin, idxw);
    vq_emit    <<<256, 256, 0, stream>>>(cb, z, idxw, outf, lossw);
    vq_finalize<<<1, 1, 0, stream>>>(lossw, outf + ZQ_ELEMS);
}

// Round 9
// 411.925 us; speedup vs baseline: 1.2601x; 1.0676x over previous
//
#include <hip/hip_runtime.h>

typedef short s8v __attribute__((ext_vector_type(8)));
typedef float f4v __attribute__((ext_vector_type(4)));
typedef float f4 __attribute__((ext_vector_type(4)));

#define N_PIX 16384
#define NE    8192
#define EDIM  256
#define ZQ_ELEMS 4194304
#define MARGIN 4.5e-4f
#define NGRP 512           // 16 codes per pruning group

__device__ __forceinline__ float bf2f(unsigned short u) {
    union { unsigned int i; float f; } c; c.i = ((unsigned int)u) << 16; return c.f;
}
__device__ __forceinline__ unsigned short f2bf(float f) {
    unsigned int u = __float_as_uint(f);
    u = (u + 0x7fffu + ((u >> 16) & 1u)) >> 16;   // RNE
    return (unsigned short)u;
}
__device__ __forceinline__ unsigned short f2bf_down(float f) {  // round toward -inf
    unsigned int u = __float_as_uint(f);
    unsigned short b = (unsigned short)(u >> 16);
    if ((u & 0xFFFFu) && (u >> 31)) b += 1;
    return b;
}

// numpy pairwise_sum over 128 squared elements (exact replication: 8
// accumulators, fixed combine tree), f32 RN ops, no FMA contraction.
__device__ __forceinline__ float np_pw128sq(const float* a) {
    float r[8];
    #pragma unroll
    for (int j = 0; j < 8; ++j) r[j] = __fmul_rn(a[j], a[j]);
    for (int i = 8; i < 128; i += 8)
        #pragma unroll
        for (int j = 0; j < 8; ++j) r[j] = __fadd_rn(r[j], __fmul_rn(a[i + j], a[i + j]));
    return __fadd_rn(__fadd_rn(__fadd_rn(r[0], r[1]), __fadd_rn(r[2], r[3])),
                     __fadd_rn(__fadd_rn(r[4], r[5]), __fadd_rn(r[6], r[7])));
}

// K0: cb16 = bf16(cb); esum32[k] = np.sum(cb[k]*cb[k]) in exact np-f32
// pairwise semantics. WS-only writes.
__global__ __launch_bounds__(256) void vq_prep(const float* __restrict__ cb,
                                               unsigned short* __restrict__ cb16,
                                               float* __restrict__ esum32) {
    int t = threadIdx.x;
    int base = blockIdx.x * 64;
    const float* src = cb + (size_t)base * EDIM;
    unsigned short* dst = cb16 + (size_t)base * EDIM;
    for (int i = 0; i < 64; ++i) dst[i * EDIM + t] = f2bf(src[i * EDIM + t]);
    if (t < 64) {
        const float* a = cb + (size_t)(base + t) * EDIM;
        esum32[base + t] = __fadd_rn(np_pw128sq(a), np_pw128sq(a + 128));
    }
}

// K1: MFMA pruning. Block = 8 waves owns 64 pixels; wave w owns codes
// [w*1024,(w+1)*1024). 16-code groups: gmin[g][pixel] = bf16_down(-2*max
// dot over group), g = wave*64 + it*2 + s. gmin lives in d_out's z_q
// chunk (16.78 MB) — overwritten later by vq_emit. Proxy error bound
// ~1.1e-4 each side < MARGIN/2.
__global__ __launch_bounds__(512, 2) void vq_phase1(const float* __restrict__ z,
                                                    const unsigned short* __restrict__ cb16,
                                                    unsigned short* __restrict__ gmin) {
    const int t = threadIdx.x;
    const int wave = t >> 6, lane = t & 63;
    const int col = lane & 15, q = lane >> 4;
    const int mb = blockIdx.x * 64;

    // A frags: A[m=lane&15][k=q*8+j]; pixel n = mb + rt*16 + m (z NCHW f32).
    s8v A[4][8];
    #pragma unroll
    for (int rt = 0; rt < 4; ++rt) {
        int n = mb + rt * 16 + col;
        const float* zb = z + ((size_t)(n >> 10) << 18) + (size_t)(n & 1023);
        #pragma unroll
        for (int c0 = 0; c0 < 8; ++c0) {
            s8v a;
            #pragma unroll
            for (int j = 0; j < 8; ++j) {
                int c = c0 * 32 + q * 8 + j;
                a[j] = (short)f2bf(zb[(size_t)c << 10]);
            }
            A[rt][c0] = a;
        }
    }

    for (int it = 0; it < 32; ++it) {
        int n0 = wave * 1024 + it * 32;
        const unsigned short* bb = cb16 + (size_t)(n0 + col) * EDIM + q * 8;
        f4v zz = {0.f, 0.f, 0.f, 0.f};
        f4v acc[4][2];
        #pragma unroll
        for (int rt = 0; rt < 4; ++rt) { acc[rt][0] = zz; acc[rt][1] = zz; }
        #pragma unroll
        for (int c0 = 0; c0 < 8; ++c0) {
            s8v B0 = *(const s8v*)(bb + c0 * 32);
            s8v B1 = *(const s8v*)(bb + 16 * EDIM + c0 * 32);
            #pragma unroll
            for (int rt = 0; rt < 4; ++rt) {
                acc[rt][0] = __builtin_amdgcn_mfma_f32_16x16x32_bf16(A[rt][c0], B0, acc[rt][0], 0, 0, 0);
                acc[rt][1] = __builtin_amdgcn_mfma_f32_16x16x32_bf16(A[rt][c0], B1, acc[rt][1], 0, 0, 0);
            }
        }
        // D: col=lane&15 (code within 16), row=q*4+r (pixel within 16-tile).
        // Separate group-min per acc half s (codes n0+s*16+col).
        #pragma unroll
        for (int rt = 0; rt < 4; ++rt) {
            #pragma unroll
            for (int r = 0; r < 4; ++r) {
                #pragma unroll
                for (int s = 0; s < 2; ++s) {
                    float mx = acc[rt][s][r];
                    #pragma unroll
                    for (int m = 1; m < 16; m <<= 1) mx = fmaxf(mx, __shfl_xor(mx, m));
                    if (col == rt * 4 + r)
                        gmin[(size_t)(wave * 64 + it * 2 + s) * N_PIX + mb + rt * 16 + q * 4 + r] =
                            f2bf_down(-2.0f * mx);
                }
            }
        }
    }
}

// K2: rescore candidate 16-code groups replicating np f32 semantics:
// d = f32(f32(zsum + esum[k]) - f32(2 * f32(dot64))), argmin with
// FIRST-INDEX tie-break. 4 waves/block, wave owns pixels 4w..4w+3.
// One group rescored by the full wave: 4 lanes per code row (coalesced
// 64 B per quad), 4 independent f64 accs, 2-shfl quad reduce, per-lane
// best + ONE deferred wave reduce per pixel.
__global__ __launch_bounds__(256) void vq_phase2(const float* __restrict__ z,
                                                 const float* __restrict__ cb,
                                                 const float* __restrict__ esum32,
                                                 const unsigned short* __restrict__ gmin,
                                                 unsigned int* __restrict__ idxw) {
    __shared__ float zt[16 * 260];
    __shared__ unsigned short gm[NGRP * 17];
    __shared__ float zs[16];
    int t = threadIdx.x;
    int wave = t >> 6, lane = t & 63;
    int p0 = blockIdx.x * 16;
    int bb = p0 >> 10, inner = p0 & 1023;

    #pragma unroll
    for (int i = 0; i < 16; ++i) {
        int c = i * 16 + (t >> 4), p = t & 15;
        zt[p * 260 + c] = z[((size_t)(bb * 256 + c) << 10) + inner + p];
    }
    #pragma unroll
    for (int i = 0; i < 32; ++i) {
        int g = i * 16 + (t >> 4), p = t & 15;
        gm[g * 17 + p] = gmin[(size_t)g * N_PIX + p0 + p];
    }
    __syncthreads();
    if (t < 16) {
        const float* a = zt + t * 260;
        zs[t] = __fadd_rn(np_pw128sq(a), np_pw128sq(a + 128));  // np zsum
    }
    __syncthreads();

    #pragma unroll
    for (int pp = 0; pp < 4; ++pp) {
        int p = wave * 4 + pp;
        float lmin = 3.0e38f;
        #pragma unroll
        for (int j = 0; j < 8; ++j) lmin = fminf(lmin, bf2f(gm[(lane * 8 + j) * 17 + p]));
        #pragma unroll
        for (int m = 1; m < 64; m <<= 1) lmin = fminf(lmin, __shfl_xor(lmin, m));
        float thr = lmin + MARGIN;
        float zsp = zs[p];

        float bd = 3.0e38f; int bk = 0x7FFFFFFF;
        for (int j = 0; j < 8; ++j) {
            unsigned long long mask = __ballot(bf2f(gm[(lane * 8 + j) * 17 + p]) <= thr);
            while (mask) {
                int lb = __builtin_ctzll(mask); mask &= mask - 1;
                int g = lb * 8 + j;
                int k = g * 16 + (lane >> 2);
                const f4* cr = (const f4*)(cb + (size_t)k * EDIM) + (lane & 3);
                const f4* zr = (const f4*)(zt + p * 260) + (lane & 3);
                double a0 = 0.0, a1 = 0.0, a2 = 0.0, a3 = 0.0;
                #pragma unroll
                for (int i = 0; i < 16; ++i) {
                    f4 x = zr[i * 4], y = cr[i * 4];
                    a0 = fma((double)x[0], (double)y[0], a0);
                    a1 = fma((double)x[1], (double)y[1], a1);
                    a2 = fma((double)x[2], (double)y[2], a2);
                    a3 = fma((double)x[3], (double)y[3], a3);
                }
                double s = (a0 + a1) + (a2 + a3);
                s += __shfl_xor(s, 1);
                s += __shfl_xor(s, 2);
                float E = (float)s;                                   // einsum f32 surrogate
                float d = __fsub_rn(__fadd_rn(zsp, esum32[k]), __fmul_rn(2.0f, E));
                if (d < bd || (d == bd && k < bk)) { bd = d; bk = k; }
            }
        }
        #pragma unroll
        for (int m = 1; m < 64; m <<= 1) {
            float od = __shfl_xor(bd, m); int ok = __shfl_xor(bk, m);
            if (od < bd || (od == bd && ok < bk)) { bd = od; bk = ok; }
        }
        if (lane == 0) idxw[p0 + p] = (unsigned int)bk;
    }
}

// K3: SOLE final writer of z_q (f32 chunk0, overwrites gmin scratch) and
// indices (f32 chunk2).
__global__ __launch_bounds__(256) void vq_emit(const float* __restrict__ cb,
                                               const float* __restrict__ z,
                                               const unsigned int* __restrict__ idxw,
                                               float* __restrict__ outf,
                                               float* __restrict__ lossw) {
    __shared__ float red[4];
    int t = threadIdx.x;
    int gtid = blockIdx.x * 256 + t;
    if (gtid < N_PIX) outf[ZQ_ELEMS + 1 + gtid] = (float)(idxw[gtid] & (NE - 1));

    float acc = 0.f;
    size_t base = (size_t)blockIdx.x * 16384;
    for (int i = 0; i < 64; ++i) {
        size_t o = base + (size_t)i * 256 + t;
        int b = (int)(o >> 18);
        int c = (int)((o >> 10) & 255);
        int p = (int)(o & 1023);
        int idx = (int)(idxw[b * 1024 + p] & (NE - 1));
        float qv = cb[(size_t)idx * EDIM + c];
        outf[o] = qv;
        float d = qv - z[o];
        acc = fmaf(d, d, acc);
    }
    #pragma unroll
    for (int off = 32; off > 0; off >>= 1) acc += __shfl_down(acc, off);
    if ((t & 63) == 0) red[t >> 6] = acc;
    __syncthreads();
    if (t == 0) atomicAdd(lossw, red[0] + red[1] + red[2] + red[3]);
}

// K4: SOLE writer of loss (f32 chunk1).
__global__ void vq_finalize(const float* __restrict__ lossw, float* __restrict__ loss_out) {
    loss_out[0] = 1.25f * lossw[0] * (1.0f / 4194304.0f);
}

extern "C" void kernel_launch(void* const* d_in, const int* in_sizes, int n_in,
                              void* d_out, int out_size, void* d_ws, size_t ws_size,
                              hipStream_t stream) {
    const float* z  = (const float*)d_in[0];   // f32 [16,256,32,32]
    const float* cb = (const float*)d_in[1];   // f32 [8192,256]
    float* outf = (float*)d_out;               // f32 [z_q | loss | indices]
    // gmin scratch (512 groups x 16384 px, u16 = 16.78 MB) lives in the z_q
    // chunk of d_out between phase1 and phase2; vq_emit overwrites it.
    unsigned short* gmin = (unsigned short*)d_out;

    char* w = (char*)d_ws;
    unsigned short* cb16   = (unsigned short*)w;               //  4,194,304 B
    float*          esum32 = (float*)(w + 4194304);            //     32,768 B
    unsigned int*   idxw   = (unsigned int*)(w + 4227072);     //     65,536 B
    float*          lossw  = (float*)(w + 4292608);            //          4 B

    if (ws_size < 4292612) return;  // diagnostic: all-zero out => ws too small

    hipMemsetAsync(lossw, 0, sizeof(float), stream);
    vq_prep    <<<NE / 64, 256, 0, stream>>>(cb, cb16, esum32);
    vq_phase1  <<<N_PIX / 64, 512, 0, stream>>>(z, cb16, gmin);
    vq_phase2  <<<N_PIX / 16, 256, 0, stream>>>(z, cb, esum32, gmin, idxw);
    vq_emit    <<<256, 256, 0, stream>>>(cb, z, idxw, outf, lossw);
    vq_finalize<<<1, 1, 0, stream>>>(lossw, outf + ZQ_ELEMS);
}

// Round 10
// 313.694 us; speedup vs baseline: 1.6546x; 1.3131x over previous
//
#include <hip/hip_runtime.h>

typedef short s8v __attribute__((ext_vector_type(8)));
typedef float f4v __attribute__((ext_vector_type(4)));
typedef float f4 __attribute__((ext_vector_type(4)));

#define N_PIX 16384
#define NE    8192
#define EDIM  256
#define ZQ_ELEMS 4194304
#define MARGIN 4.5e-4f
#define NGRP 512           // 16 codes per pruning group

__device__ __forceinline__ float bf2f(unsigned short u) {
    union { unsigned int i; float f; } c; c.i = ((unsigned int)u) << 16; return c.f;
}
__device__ __forceinline__ unsigned short f2bf(float f) {
    unsigned int u = __float_as_uint(f);
    u = (u + 0x7fffu + ((u >> 16) & 1u)) >> 16;   // RNE
    return (unsigned short)u;
}
__device__ __forceinline__ unsigned short f2bf_down(float f) {  // round toward -inf
    unsigned int u = __float_as_uint(f);
    unsigned short b = (unsigned short)(u >> 16);
    if ((u & 0xFFFFu) && (u >> 31)) b += 1;
    return b;
}

// numpy pairwise_sum over 128 squared elements (exact replication: 8
// accumulators, fixed combine tree), f32 RN ops, no FMA contraction.
__device__ __forceinline__ float np_pw128sq(const float* a) {
    float r[8];
    #pragma unroll
    for (int j = 0; j < 8; ++j) r[j] = __fmul_rn(a[j], a[j]);
    for (int i = 8; i < 128; i += 8)
        #pragma unroll
        for (int j = 0; j < 8; ++j) r[j] = __fadd_rn(r[j], __fmul_rn(a[i + j], a[i + j]));
    return __fadd_rn(__fadd_rn(__fadd_rn(r[0], r[1]), __fadd_rn(r[2], r[3])),
                     __fadd_rn(__fadd_rn(r[4], r[5]), __fadd_rn(r[6], r[7])));
}

// K0: cb16 = bf16(cb); esum32[k] = np.sum(cb[k]*cb[k]) in exact np-f32
// pairwise semantics. WS-only writes.
__global__ __launch_bounds__(256) void vq_prep(const float* __restrict__ cb,
                                               unsigned short* __restrict__ cb16,
                                               float* __restrict__ esum32) {
    int t = threadIdx.x;
    int base = blockIdx.x * 64;
    const float* src = cb + (size_t)base * EDIM;
    unsigned short* dst = cb16 + (size_t)base * EDIM;
    for (int i = 0; i < 64; ++i) dst[i * EDIM + t] = f2bf(src[i * EDIM + t]);
    if (t < 64) {
        const float* a = cb + (size_t)(base + t) * EDIM;
        esum32[base + t] = __fadd_rn(np_pw128sq(a), np_pw128sq(a + 128));
    }
}

// K1: MFMA pruning, OPERAND-SWAPPED (A=codes, B=pixels => D col=pixel,
// row=code): per-lane regs hold 4 codes of one pixel, so the 16-code
// group-max is 3 local fmax + 2 shfl (xor16,32), store is a coalesced
// 16-lane row. Grid 512: block bx owns pixels (bx>>1)*64 and code half
// (bx&1)*4096; wave owns 512 codes (16 its x 32). gmin[g][pixel] =
// bf16_down(-2*max dot), g = (bx&1)*256 + wave*32 + it*2 + s; parked in
// d_out's z_q chunk, overwritten later by vq_emit.
__global__ __launch_bounds__(512, 2) void vq_phase1(const float* __restrict__ z,
                                                    const unsigned short* __restrict__ cb16,
                                                    unsigned short* __restrict__ gmin) {
    const int t = threadIdx.x;
    const int wave = t >> 6, lane = t & 63;
    const int col = lane & 15, q = lane >> 4;
    const int mb = (blockIdx.x >> 1) * 64;
    const int chalf = blockIdx.x & 1;

    // z frags (B operand): B[n=lane&15=pixel][k=q*8+j]; pixel n = mb+pt*16+col.
    s8v Z[4][8];
    #pragma unroll
    for (int pt = 0; pt < 4; ++pt) {
        int n = mb + pt * 16 + col;
        const float* zb = z + ((size_t)(n >> 10) << 18) + (size_t)(n & 1023);
        #pragma unroll
        for (int c0 = 0; c0 < 8; ++c0) {
            s8v a;
            #pragma unroll
            for (int j = 0; j < 8; ++j) {
                int c = c0 * 32 + q * 8 + j;
                a[j] = (short)f2bf(zb[(size_t)c << 10]);
            }
            Z[pt][c0] = a;
        }
    }

    const int kbase = chalf * 4096 + wave * 512;
    for (int it = 0; it < 16; ++it) {
        int n0 = kbase + it * 32;
        const unsigned short* bb = cb16 + (size_t)(n0 + col) * EDIM + q * 8;
        f4v zz = {0.f, 0.f, 0.f, 0.f};
        f4v acc[4][2];
        #pragma unroll
        for (int pt = 0; pt < 4; ++pt) { acc[pt][0] = zz; acc[pt][1] = zz; }
        #pragma unroll
        for (int c0 = 0; c0 < 8; ++c0) {
            s8v C0 = *(const s8v*)(bb + c0 * 32);             // codes n0+col (A operand)
            s8v C1 = *(const s8v*)(bb + 16 * EDIM + c0 * 32); // codes n0+16+col
            #pragma unroll
            for (int pt = 0; pt < 4; ++pt) {
                acc[pt][0] = __builtin_amdgcn_mfma_f32_16x16x32_bf16(C0, Z[pt][c0], acc[pt][0], 0, 0, 0);
                acc[pt][1] = __builtin_amdgcn_mfma_f32_16x16x32_bf16(C1, Z[pt][c0], acc[pt][1], 0, 0, 0);
            }
        }
        // D: col=lane&15 (pixel), row=q*4+r (code within 16). Group-max:
        int gbase = chalf * 256 + wave * 32 + it * 2;
        #pragma unroll
        for (int pt = 0; pt < 4; ++pt) {
            #pragma unroll
            for (int s = 0; s < 2; ++s) {
                f4v a = acc[pt][s];
                float mx = fmaxf(fmaxf(a[0], a[1]), fmaxf(a[2], a[3]));
                mx = fmaxf(mx, __shfl_xor(mx, 16));
                mx = fmaxf(mx, __shfl_xor(mx, 32));
                if (q == 0)
                    gmin[(size_t)(gbase + s) * N_PIX + mb + pt * 16 + col] =
                        f2bf_down(-2.0f * mx);
            }
        }
    }
}

// K2: rescore candidate 16-code groups replicating np f32 semantics:
// d = f32(f32(zsum + esum[k]) - f32(2 * f32(dot64))), argmin with
// FIRST-INDEX tie-break. 4 waves/block, wave owns pixels 4w..4w+3.
// One group rescored by the full wave: 4 lanes per code row (coalesced
// 64 B per quad), 4 independent f64 accs, 2-shfl quad reduce, per-lane
// best + ONE deferred wave reduce per pixel.
__global__ __launch_bounds__(256) void vq_phase2(const float* __restrict__ z,
                                                 const float* __restrict__ cb,
                                                 const float* __restrict__ esum32,
                                                 const unsigned short* __restrict__ gmin,
                                                 unsigned int* __restrict__ idxw) {
    __shared__ float zt[16 * 260];
    __shared__ unsigned short gm[NGRP * 17];
    __shared__ float zs[16];
    int t = threadIdx.x;
    int wave = t >> 6, lane = t & 63;
    int p0 = blockIdx.x * 16;
    int bb = p0 >> 10, inner = p0 & 1023;

    #pragma unroll
    for (int i = 0; i < 16; ++i) {
        int c = i * 16 + (t >> 4), p = t & 15;
        zt[p * 260 + c] = z[((size_t)(bb * 256 + c) << 10) + inner + p];
    }
    #pragma unroll
    for (int i = 0; i < 32; ++i) {
        int g = i * 16 + (t >> 4), p = t & 15;
        gm[g * 17 + p] = gmin[(size_t)g * N_PIX + p0 + p];
    }
    __syncthreads();
    if (t < 16) {
        const float* a = zt + t * 260;
        zs[t] = __fadd_rn(np_pw128sq(a), np_pw128sq(a + 128));  // np zsum
    }
    __syncthreads();

    #pragma unroll
    for (int pp = 0; pp < 4; ++pp) {
        int p = wave * 4 + pp;
        float lmin = 3.0e38f;
        #pragma unroll
        for (int j = 0; j < 8; ++j) lmin = fminf(lmin, bf2f(gm[(lane * 8 + j) * 17 + p]));
        #pragma unroll
        for (int m = 1; m < 64; m <<= 1) lmin = fminf(lmin, __shfl_xor(lmin, m));
        float thr = lmin + MARGIN;
        float zsp = zs[p];

        float bd = 3.0e38f; int bk = 0x7FFFFFFF;
        for (int j = 0; j < 8; ++j) {
            unsigned long long mask = __ballot(bf2f(gm[(lane * 8 + j) * 17 + p]) <= thr);
            while (mask) {
                int lb = __builtin_ctzll(mask); mask &= mask - 1;
                int g = lb * 8 + j;
                int k = g * 16 + (lane >> 2);
                const f4* cr = (const f4*)(cb + (size_t)k * EDIM) + (lane & 3);
                const f4* zr = (const f4*)(zt + p * 260) + (lane & 3);
                double a0 = 0.0, a1 = 0.0, a2 = 0.0, a3 = 0.0;
                #pragma unroll
                for (int i = 0; i < 16; ++i) {
                    f4 x = zr[i * 4], y = cr[i * 4];
                    a0 = fma((double)x[0], (double)y[0], a0);
                    a1 = fma((double)x[1], (double)y[1], a1);
                    a2 = fma((double)x[2], (double)y[2], a2);
                    a3 = fma((double)x[3], (double)y[3], a3);
                }
                double s = (a0 + a1) + (a2 + a3);
                s += __shfl_xor(s, 1);
                s += __shfl_xor(s, 2);
                float E = (float)s;                                   // einsum f32 surrogate
                float d = __fsub_rn(__fadd_rn(zsp, esum32[k]), __fmul_rn(2.0f, E));
                if (d < bd || (d == bd && k < bk)) { bd = d; bk = k; }
            }
        }
        #pragma unroll
        for (int m = 1; m < 64; m <<= 1) {
            float od = __shfl_xor(bd, m); int ok = __shfl_xor(bk, m);
            if (od < bd || (od == bd && ok < bk)) { bd = od; bk = ok; }
        }
        if (lane == 0) idxw[p0 + p] = (unsigned int)bk;
    }
}

// K3: SOLE final writer of z_q (f32 chunk0, overwrites gmin scratch) and
// indices (f32 chunk2).
__global__ __launch_bounds__(256) void vq_emit(const float* __restrict__ cb,
                                               const float* __restrict__ z,
                                               const unsigned int* __restrict__ idxw,
                                               float* __restrict__ outf,
                                               float* __restrict__ lossw) {
    __shared__ float red[4];
    int t = threadIdx.x;
    int gtid = blockIdx.x * 256 + t;
    if (gtid < N_PIX) outf[ZQ_ELEMS + 1 + gtid] = (float)(idxw[gtid] & (NE - 1));

    float acc = 0.f;
    size_t base = (size_t)blockIdx.x * 16384;
    for (int i = 0; i < 64; ++i) {
        size_t o = base + (size_t)i * 256 + t;
        int b = (int)(o >> 18);
        int c = (int)((o >> 10) & 255);
        int p = (int)(o & 1023);
        int idx = (int)(idxw[b * 1024 + p] & (NE - 1));
        float qv = cb[(size_t)idx * EDIM + c];
        outf[o] = qv;
        float d = qv - z[o];
        acc = fmaf(d, d, acc);
    }
    #pragma unroll
    for (int off = 32; off > 0; off >>= 1) acc += __shfl_down(acc, off);
    if ((t & 63) == 0) red[t >> 6] = acc;
    __syncthreads();
    if (t == 0) atomicAdd(lossw, red[0] + red[1] + red[2] + red[3]);
}

// K4: SOLE writer of loss (f32 chunk1).
__global__ void vq_finalize(const float* __restrict__ lossw, float* __restrict__ loss_out) {
    loss_out[0] = 1.25f * lossw[0] * (1.0f / 4194304.0f);
}

extern "C" void kernel_launch(void* const* d_in, const int* in_sizes, int n_in,
                              void* d_out, int out_size, void* d_ws, size_t ws_size,
                              hipStream_t stream) {
    const float* z  = (const float*)d_in[0];   // f32 [16,256,32,32]
    const float* cb = (const float*)d_in[1];   // f32 [8192,256]
    float* outf = (float*)d_out;               // f32 [z_q | loss | indices]
    // gmin scratch (512 groups x 16384 px, u16 = 16.78 MB) lives in the z_q
    // chunk of d_out between phase1 and phase2; vq_emit overwrites it.
    unsigned short* gmin = (unsigned short*)d_out;

    char* w = (char*)d_ws;
    unsigned short* cb16   = (unsigned short*)w;               //  4,194,304 B
    float*          esum32 = (float*)(w + 4194304);            //     32,768 B
    unsigned int*   idxw   = (unsigned int*)(w + 4227072);     //     65,536 B
    float*          lossw  = (float*)(w + 4292608);            //          4 B

    if (ws_size < 4292612) return;  // diagnostic: all-zero out => ws too small

    hipMemsetAsync(lossw, 0, sizeof(float), stream);
    vq_prep    <<<NE / 64, 256, 0, stream>>>(cb, cb16, esum32);
    vq_phase1  <<<(N_PIX / 64) * 2, 512, 0, stream>>>(z, cb16, gmin);
    vq_phase2  <<<N_PIX / 16, 256, 0, stream>>>(z, cb, esum32, gmin, idxw);
    vq_emit    <<<256, 256, 0, stream>>>(cb, z, idxw, outf, lossw);
    vq_finalize<<<1, 1, 0, stream>>>(lossw, outf + ZQ_ELEMS);
}